// Round 12
// baseline (134.279 us; speedup 1.0000x reference)
//
#include <hip/hip_runtime.h>
#include <cstdint>
#include <cstddef>
#include <cmath>

// ---------------------------------------------------------------------------
// MultiHeadAttention (B=2, S=2048, DIM=1024, H=16, HD=64), causal + RoPE.
// R12 = R11 with the compile fix (__exp2f -> exp2f; clang lowers exp2f to
// v_exp_f32 at -O3). attn: R4-proven simple body + exp2 softmax + paired max
// tree. GEMMs (BK=64 swizzled), prep, rope, trans, aliasing identical to R10.
// ---------------------------------------------------------------------------

typedef __bf16 bf16_t;
typedef __bf16 bf16x8 __attribute__((ext_vector_type(8)));
typedef __bf16 bf16x4 __attribute__((ext_vector_type(4)));
typedef float  f32x4  __attribute__((ext_vector_type(4)));

#define DEVFN __device__ __forceinline__

static constexpr int Bn  = 2;
static constexpr int S   = 2048;
static constexpr int DIM = 1024;
static constexpr int NH  = 16;
static constexpr int HD  = 64;
static constexpr int Mrows = Bn * S;        // 4096

DEVFN f32x4 mfma16(bf16x8 a, bf16x8 b, f32x4 c) {
  return __builtin_amdgcn_mfma_f32_16x16x32_bf16(a, b, c, 0, 0, 0);
}

DEVFN void gl_lds16(const bf16_t* g, bf16_t* l) {
  __builtin_amdgcn_global_load_lds(
      (const __attribute__((address_space(1))) unsigned*)g,
      (__attribute__((address_space(3))) unsigned*)l, 16, 0, 0);
}

DEVFN float fast_exp2(float x) { return exp2f(x); }  // -> v_exp_f32

// ---------------------------------------------------------------------------
// One launch: all fp32->bf16 converts + rope table.
__global__ __launch_bounds__(256) void k_prep(
    const float* __restrict__ x, const float* __restrict__ wq,
    const float* __restrict__ wk, const float* __restrict__ wv,
    const float* __restrict__ wo, bf16_t* __restrict__ xb,
    bf16_t* __restrict__ wqb, bf16_t* __restrict__ wkb,
    bf16_t* __restrict__ wvb, bf16_t* __restrict__ wob,
    float2* __restrict__ tab) {
  const int bid = blockIdx.x;
  if (bid < 8192) {
    const float* src;
    bf16_t* dst;
    size_t base;
    if (bid < 4096) {
      src = x; dst = xb; base = (size_t)bid << 10;
    } else {
      int wsel = (bid - 4096) >> 10;
      src = wsel == 0 ? wq : wsel == 1 ? wk : wsel == 2 ? wv : wo;
      dst = wsel == 0 ? wqb : wsel == 1 ? wkb : wsel == 2 ? wvb : wob;
      base = (size_t)((bid - 4096) & 1023) << 10;
    }
    size_t i = base + (size_t)threadIdx.x * 4;
    float4 v = *(const float4*)(src + i);
    bf16x4 o = { (bf16_t)v.x, (bf16_t)v.y, (bf16_t)v.z, (bf16_t)v.w };
    *(bf16x4*)(dst + i) = o;
  } else {
    int i = (bid - 8192) * 256 + threadIdx.x;  // < S*32
    int s = i >> 5, d = i & 31;
    float th = (float)s * expf((float)d * -0.2878231366f);  // ln(10000)/32
    tab[i] = make_float2(cosf(th), sinf(th));
  }
}

// ---------------------------------------------------------------------------
// in-place rope on [Mrows][DIM] bf16 (R4-proven body).
__global__ __launch_bounds__(256) void k_rope(bf16_t* __restrict__ X,
                                              const float2* __restrict__ tab,
                                              float scale) {
  int i = blockIdx.x * 256 + threadIdx.x;   // chunk of 8 elems
  int row = i >> 7;
  int s = row & (S - 1);
  int dd = (i & 7) << 3;
  int p0 = dd >> 1;
  bf16x8 v = *(bf16x8*)(X + (size_t)i * 8);
  bf16x8 o;
#pragma unroll
  for (int j = 0; j < 4; ++j) {
    float x1 = (float)v[2 * j], x2 = (float)v[2 * j + 1];
    float2 cs = tab[s * 32 + p0 + j];
    o[2 * j]     = (bf16_t)((x1 * cs.x - x2 * cs.y) * scale);
    o[2 * j + 1] = (bf16_t)((x1 * cs.y + x2 * cs.x) * scale);
  }
  *(bf16x8*)(X + (size_t)i * 8) = o;
}

// V [b][s][h][d] -> VT [b*h][d][s] (R4-proven body).
__global__ __launch_bounds__(256) void k_trans(const bf16_t* __restrict__ Vin,
                                               bf16_t* __restrict__ VT) {
  __shared__ __align__(16) bf16_t tile[64][72];
  int s0 = blockIdx.x * 64, bh = blockIdx.y;
  int b = bh >> 4, h = bh & 15;
  int t = threadIdx.x;
#pragma unroll
  for (int it = 0; it < 2; ++it) {
    int sl = (t >> 3) + it * 32, d0 = (t & 7) << 3;
    *(bf16x8*)&tile[sl][d0] =
        *(const bf16x8*)(Vin + (size_t)(b * S + s0 + sl) * DIM + h * HD + d0);
  }
  __syncthreads();
  int d = t >> 2, c0 = (t & 3) * 16;
  bf16_t buf[16];
#pragma unroll
  for (int j = 0; j < 16; ++j) buf[j] = tile[c0 + j][d];
  bf16_t* op = VT + ((size_t)bh * HD + d) * S + s0 + c0;
  *(bf16x8*)op = *(bf16x8*)&buf[0];
  *(bf16x8*)(op + 8) = *(bf16x8*)&buf[8];
}

// ---------------------------------------------------------------------------
// GEMM staging, BK=64 tile [128 rows][64 k] per matrix. Source pre-swizzled
// j=((c&7)^(row&7))*8, LDS dest linear; read back with byte-XOR ((row&7)<<4).
DEVFN void stage64(const bf16_t* __restrict__ A, const bf16_t* __restrict__ Bw,
                   bf16_t* Al, bf16_t* Bl, int m0, int n0, int k0, int t,
                   int w) {
#pragma unroll
  for (int ld = 0; ld < 4; ++ld) {
    int c = t + ld * 256;
    int row = c >> 3;
    int j = ((c & 7) ^ (row & 7)) << 3;
    bf16_t* dstA = Al + (size_t)(w * 64 + ld * 256) * 8;
    bf16_t* dstB = Bl + (size_t)(w * 64 + ld * 256) * 8;
    gl_lds16(A + (size_t)(m0 + row) * DIM + k0 + j, dstA);
    gl_lds16(Bw + (size_t)(n0 + row) * DIM + k0 + j, dstB);
  }
}

// ---------------------------------------------------------------------------
// Fused QKV NT GEMM: M=4096, N=3072 (wq|wk|wv contiguous), K=1024. 128x128
// tile, BK=64 (16 iters). 768 blocks, XCD rectangle swizzle. Plain bias
// epilogue -> q_lin/k_lin/v_lin.
__global__ __launch_bounds__(256) void k_gemm_qkv(
    const bf16_t* __restrict__ A, const bf16_t* __restrict__ Wall,
    const float* __restrict__ c0, const float* __restrict__ c1,
    const float* __restrict__ c2, bf16_t* __restrict__ Oq,
    bf16_t* __restrict__ Ok, bf16_t* __restrict__ Ov_) {
  __shared__ __align__(16) bf16_t Al[128 * 64];
  __shared__ __align__(16) bf16_t Bl[128 * 64];
  const int t = threadIdx.x, w = t >> 6, l = t & 63;
  const int lr = l & 15, lc = l >> 4;
  const int lid = blockIdx.x;
  const int xcd = lid & 7, s = lid >> 3;          // s in [0,96)
  const int my = ((xcd >> 1) << 3) + (s & 7);     // [0,32)
  const int nx = (xcd & 1) * 12 + (s >> 3);       // [0,24)
  const int m0 = my * 128, n0g = nx * 128;
  const int z = n0g >> 10, n0l = n0g & 1023;
  const int wr = w >> 1, wc = w & 1;
  f32x4 acc[4][4] = {};

  for (int k0 = 0; k0 < DIM; k0 += 64) {
    __syncthreads();
    stage64(A, Wall, Al, Bl, m0, n0g, k0, t, w);
    asm volatile("s_waitcnt vmcnt(0)" ::: "memory");  // belt-and-braces drain
    __syncthreads();
    bf16x8 af[2][4], bfr[2][4];
#pragma unroll
    for (int ks = 0; ks < 2; ++ks) {
#pragma unroll
      for (int mi = 0; mi < 4; ++mi) {
        int row = wr * 64 + mi * 16 + lr;
        int off = ((ks * 4 + lc) << 4) ^ ((row & 7) << 4);
        af[ks][mi] = *(const bf16x8*)((const char*)Al + row * 128 + off);
      }
#pragma unroll
      for (int ni = 0; ni < 4; ++ni) {
        int row = wc * 64 + ni * 16 + lr;
        int off = ((ks * 4 + lc) << 4) ^ ((row & 7) << 4);
        bfr[ks][ni] = *(const bf16x8*)((const char*)Bl + row * 128 + off);
      }
    }
    __builtin_amdgcn_s_setprio(1);
#pragma unroll
    for (int ks = 0; ks < 2; ++ks)
#pragma unroll
      for (int mi = 0; mi < 4; ++mi)
#pragma unroll
        for (int ni = 0; ni < 4; ++ni)
          acc[mi][ni] = mfma16(af[ks][mi], bfr[ks][ni], acc[mi][ni]);
    __builtin_amdgcn_s_setprio(0);
  }

  bf16_t* Ov = z == 0 ? Oq : (z == 1 ? Ok : Ov_);
  const float* bias = z == 0 ? c0 : (z == 1 ? c1 : c2);
#pragma unroll
  for (int ni = 0; ni < 4; ++ni) {
    const int col = n0l + wc * 64 + ni * 16 + lr;
    const float bv = bias[col];
#pragma unroll
    for (int mi = 0; mi < 4; ++mi)
#pragma unroll
      for (int r = 0; r < 4; ++r) {
        int row = m0 + wr * 64 + mi * 16 + lc * 4 + r;
        Ov[(size_t)row * DIM + col] = (bf16_t)(acc[mi][ni][r] + bv);
      }
  }
}

// ---------------------------------------------------------------------------
// Out projection: M=4096, N=1024, K=1024. 256 blocks, same BK=64 loop.
__global__ __launch_bounds__(256) void k_gemm_out(
    const bf16_t* __restrict__ A, const bf16_t* __restrict__ Bw,
    const float* __restrict__ bias, float* __restrict__ Ov) {
  __shared__ __align__(16) bf16_t Al[128 * 64];
  __shared__ __align__(16) bf16_t Bl[128 * 64];
  const int t = threadIdx.x, w = t >> 6, l = t & 63;
  const int lr = l & 15, lc = l >> 4;
  const int lid = blockIdx.x;
  const int xcd = lid & 7, s = lid >> 3;          // s in [0,32)
  const int my = ((xcd >> 1) << 3) + (s & 7);     // [0,32)
  const int nx = (xcd & 1) * 4 + (s >> 3);        // [0,8)
  const int m0 = my * 128, n0 = nx * 128;
  const int wr = w >> 1, wc = w & 1;
  f32x4 acc[4][4] = {};

  for (int k0 = 0; k0 < DIM; k0 += 64) {
    __syncthreads();
    stage64(A, Bw, Al, Bl, m0, n0, k0, t, w);
    asm volatile("s_waitcnt vmcnt(0)" ::: "memory");  // belt-and-braces drain
    __syncthreads();
    bf16x8 af[2][4], bfr[2][4];
#pragma unroll
    for (int ks = 0; ks < 2; ++ks) {
#pragma unroll
      for (int mi = 0; mi < 4; ++mi) {
        int row = wr * 64 + mi * 16 + lr;
        int off = ((ks * 4 + lc) << 4) ^ ((row & 7) << 4);
        af[ks][mi] = *(const bf16x8*)((const char*)Al + row * 128 + off);
      }
#pragma unroll
      for (int ni = 0; ni < 4; ++ni) {
        int row = wc * 64 + ni * 16 + lr;
        int off = ((ks * 4 + lc) << 4) ^ ((row & 7) << 4);
        bfr[ks][ni] = *(const bf16x8*)((const char*)Bl + row * 128 + off);
      }
    }
    __builtin_amdgcn_s_setprio(1);
#pragma unroll
    for (int ks = 0; ks < 2; ++ks)
#pragma unroll
      for (int mi = 0; mi < 4; ++mi)
#pragma unroll
        for (int ni = 0; ni < 4; ++ni)
          acc[mi][ni] = mfma16(af[ks][mi], bfr[ks][ni], acc[mi][ni]);
    __builtin_amdgcn_s_setprio(0);
  }

#pragma unroll
  for (int ni = 0; ni < 4; ++ni) {
    int col = n0 + wc * 64 + ni * 16 + lr;
    float bv = bias[col];
#pragma unroll
    for (int mi = 0; mi < 4; ++mi)
#pragma unroll
      for (int r = 0; r < 4; ++r) {
        int row = m0 + wr * 64 + mi * 16 + lc * 4 + r;
        Ov[(size_t)row * DIM + col] = acc[mi][ni][r] + bv;
      }
  }
}

// ---------------------------------------------------------------------------
// Causal flash attention — R4-proven simple body + exp2 softmax.
// Paired q-tiles (a, 31-a): uniform 33 KV iterations. Swapped QK^T
// (s = mfma(K,Q)): lane (lr,lc) holds S'[q=w*16+lr][k=ni*16+lc*4+r] in
// log2 units (log2(e) folded into Q rope scale). K/V dbuf in LDS via
// global_load_lds (pre-swizzled source), stage(t+1) in-loop, counted
// vmcnt(4). Defer-max THR=8 (P bounded by 2^8). XCD remap: 4 heads/XCD.
DEVFN void stage_kv(const bf16_t* __restrict__ Kc,
                    const bf16_t* __restrict__ VT, bf16_t* Kb, bf16_t* Vb,
                    int b, int bh, int h, int k0, int tid, int w) {
#pragma unroll
  for (int ld = 0; ld < 2; ++ld) {
    int c = tid + ld * 256;
    int row = c >> 3;
    int j = ((c & 7) ^ (row & 7)) << 3;  // pre-swizzled source chunk
    bf16_t* dstK = Kb + (size_t)(w * 64 + ld * 256) * 8;
    bf16_t* dstV = Vb + (size_t)(w * 64 + ld * 256) * 8;
    gl_lds16(Kc + (size_t)(b * S + k0 + row) * DIM + h * HD + j, dstK);
    gl_lds16(VT + ((size_t)bh * HD + row) * S + k0 + j, dstV);
  }
}

__global__ __launch_bounds__(256) void k_attn(const bf16_t* __restrict__ Q,
                                              const bf16_t* __restrict__ Kc,
                                              const bf16_t* __restrict__ VT,
                                              bf16_t* __restrict__ O) {
  __shared__ __align__(16) bf16_t Kl[2][64 * 64];
  __shared__ __align__(16) bf16_t Vl[2][64 * 64];
  __shared__ __align__(16) bf16_t Pl[4][16 * 64];
  const int tid = threadIdx.x, w = tid >> 6, l = tid & 63;
  const int lr = l & 15, lc = l >> 4;
  const int lid = blockIdx.x + (blockIdx.y << 4);
  const int xcd = lid & 7, slot = lid >> 3;
  const int bh = xcd * 4 + (slot >> 4);
  const int a = slot & 15;
  const int b = bh >> 4, h = bh & 15;
  char* Pw = (char*)&Pl[w][0];

#pragma unroll 1
  for (int pi = 0; pi < 2; ++pi) {
    const int tile = (pi == 0) ? a : 31 - a;
    const int q0 = tile * 64;
    const int nt = tile + 1;

    bf16x8 qf[2];
    {
      const bf16_t* qp =
          Q + (size_t)(b * S + q0 + w * 16 + lr) * DIM + h * HD + lc * 8;
      qf[0] = *(const bf16x8*)qp;
      qf[1] = *(const bf16x8*)(qp + 32);
    }
    f32x4 o[4] = {};
    float m_run = -INFINITY;
    float rowsum = 0.f;

    // prologue: stage tile 0
    stage_kv(Kc, VT, &Kl[0][0], &Vl[0][0], b, bh, h, 0, tid, w);

#pragma unroll 1
    for (int it = 0; it < nt; ++it) {
      const int cur = it & 1;
      const bf16_t* Kb = &Kl[cur][0];
      const bf16_t* Vb = &Vl[cur][0];
      if (it + 1 < nt) {
        stage_kv(Kc, VT, &Kl[cur ^ 1][0], &Vl[cur ^ 1][0], b, bh, h,
                 (it + 1) * 64, tid, w);
        asm volatile("s_waitcnt vmcnt(4)" ::: "memory");
      } else {
        asm volatile("s_waitcnt vmcnt(0)" ::: "memory");
      }
      __builtin_amdgcn_s_barrier();
      __builtin_amdgcn_sched_barrier(0);

      // swapped QK^T: lane (lr,lc) holds S'[q=w*16+lr][k=ni*16+lc*4+r]
      f32x4 s[4] = {};
      __builtin_amdgcn_s_setprio(1);
#pragma unroll
      for (int ks = 0; ks < 2; ++ks) {
#pragma unroll
        for (int ni = 0; ni < 4; ++ni) {
          int row = ni * 16 + lr;
          int off = (ks * 64 + lc * 16) ^ ((row & 7) << 4);
          bf16x8 kf = *(const bf16x8*)((const char*)Kb + row * 128 + off);
          s[ni] = mfma16(kf, qf[ks], s[ni]);
        }
      }
      __builtin_amdgcn_s_setprio(0);

      if (it == tile) {  // diagonal tile: mask k_local > q_local
        const int qloc = w * 16 + lr;
#pragma unroll
        for (int ni = 0; ni < 4; ++ni)
#pragma unroll
          for (int r = 0; r < 4; ++r)
            if (ni * 16 + lc * 4 + r > qloc) s[ni][r] = -INFINITY;
      }

      // row max: paired tree (v_max3-friendly), then 2 cross-lane reduces
      float m01 = fmaxf(fmaxf(s[0][0], s[0][1]), fmaxf(s[0][2], s[0][3]));
      float m23 = fmaxf(fmaxf(s[1][0], s[1][1]), fmaxf(s[1][2], s[1][3]));
      float m45 = fmaxf(fmaxf(s[2][0], s[2][1]), fmaxf(s[2][2], s[2][3]));
      float m67 = fmaxf(fmaxf(s[3][0], s[3][1]), fmaxf(s[3][2], s[3][3]));
      float pm = fmaxf(fmaxf(m01, m23), fmaxf(m45, m67));
      pm = fmaxf(pm, __shfl_xor(pm, 16));
      pm = fmaxf(pm, __shfl_xor(pm, 32));

      // defer-max (log2 units): rescale only if max grew past 8 (P <= 2^8)
      if (__ballot(pm > m_run + 8.f)) {
        float mn = fmaxf(m_run, pm);
        float alpha = fast_exp2(m_run - mn);
        m_run = mn;
        rowsum *= alpha;
#pragma unroll
        for (int r = 0; r < 4; ++r) {
          float aq = __shfl(alpha, lc * 4 + r);
#pragma unroll
          for (int ni = 0; ni < 4; ++ni) o[ni][r] *= aq;
        }
      }

      // P = exp2(s - m_run); in-lane partial sum; pack to LDS as b64
      float rs = 0.f;
#pragma unroll
      for (int ni = 0; ni < 4; ++ni) {
        float p0 = fast_exp2(s[ni][0] - m_run);
        float p1 = fast_exp2(s[ni][1] - m_run);
        float p2 = fast_exp2(s[ni][2] - m_run);
        float p3 = fast_exp2(s[ni][3] - m_run);
        rs += (p0 + p1) + (p2 + p3);
        bf16x4 pb = { (bf16_t)p0, (bf16_t)p1, (bf16_t)p2, (bf16_t)p3 };
        *(bf16x4*)(Pw + (lr * 128 + ((ni * 32 + lc * 8) ^ ((lr & 7) << 4)))) =
            pb;
      }
      rs += __shfl_xor(rs, 16);
      rs += __shfl_xor(rs, 32);
      rowsum += rs;

      // PV: o[ni] += P(16x64) * V(64x64)
      __builtin_amdgcn_s_setprio(1);
#pragma unroll
      for (int ks = 0; ks < 2; ++ks) {
        int off = ks * 64 + lc * 16;
        bf16x8 pa =
            *(const bf16x8*)(Pw + lr * 128 + (off ^ ((lr & 7) << 4)));
#pragma unroll
        for (int ni = 0; ni < 4; ++ni) {
          int vrow = ni * 16 + lr;
          bf16x8 vb = *(const bf16x8*)((const char*)Vb + vrow * 128 +
                                       (off ^ ((vrow & 7) << 4)));
          o[ni] = mfma16(pa, vb, o[ni]);
        }
      }
      __builtin_amdgcn_s_setprio(0);

      __builtin_amdgcn_s_barrier();  // compute done before next stage overwrite
    }

    // normalize + store. o[ni]: q = q0 + w*16 + lc*4 + r, d = ni*16 + lr
    float inv[4];
#pragma unroll
    for (int r = 0; r < 4; ++r) inv[r] = 1.0f / __shfl(rowsum, lc * 4 + r);
#pragma unroll
    for (int ni = 0; ni < 4; ++ni)
#pragma unroll
      for (int r = 0; r < 4; ++r) {
        int qr = q0 + w * 16 + lc * 4 + r;
        float v = o[ni][r] * inv[r];
        O[(size_t)(b * S + qr) * DIM + h * HD + ni * 16 + lr] = (bf16_t)v;
      }
  }
}

// ---------------------------------------------------------------------------
extern "C" void kernel_launch(void* const* d_in, const int* in_sizes, int n_in,
                              void* d_out, int out_size, void* d_ws,
                              size_t ws_size, hipStream_t stream) {
  const float* x  = (const float*)d_in[0];
  const float* wq = (const float*)d_in[1];
  const float* bq = (const float*)d_in[2];
  const float* wk = (const float*)d_in[3];
  const float* bk = (const float*)d_in[4];
  const float* wv = (const float*)d_in[5];
  const float* bv = (const float*)d_in[6];
  const float* wo = (const float*)d_in[7];
  const float* bo = (const float*)d_in[8];

  const size_t MD = (size_t)Mrows * DIM;   // 4194304
  const size_t WD = (size_t)DIM * DIM;     // 1048576
  bf16_t* W = (bf16_t*)d_ws;
  bf16_t* x_bf  = W;
  bf16_t* wq_bf = x_bf + MD;               // wq|wk|wv contiguous = [3072][1024]
  bf16_t* wk_bf = wq_bf + WD;
  bf16_t* wv_bf = wk_bf + WD;
  bf16_t* wo_bf = wv_bf + WD;
  bf16_t* q_lin = wo_bf + WD;
  bf16_t* k_lin = q_lin + MD;
  bf16_t* v_lin = k_lin + MD;
  bf16_t* vT    = v_lin + MD;
  float2* tab   = (float2*)(vT + MD);
  bf16_t* attn_out = x_bf;  // x_bf dead after k_gemm_qkv; rewritten by k_prep
                            // every call -> no cross-call state dependency

  k_prep<<<8448, 256, 0, stream>>>(x, wq, wk, wv, wo, x_bf, wq_bf, wk_bf,
                                   wv_bf, wo_bf, tab);

  k_gemm_qkv<<<768, 256, 0, stream>>>(x_bf, wq_bf, bq, bk, bv, q_lin, k_lin,
                                      v_lin);

  // Q scale folds 1/sqrt(64) AND log2(e) -> QK^T scores land in log2 units.
  k_rope<<<2048, 256, 0, stream>>>(q_lin, tab, 0.125f * 1.4426950408889634f);
  k_rope<<<2048, 256, 0, stream>>>(k_lin, tab, 1.0f);
  k_trans<<<dim3(S / 64, Bn * NH), 256, 0, stream>>>(v_lin, vT);

  k_attn<<<dim3(16, Bn * NH), 256, 0, stream>>>(q_lin, k_lin, vT, attn_out);

  k_gemm_out<<<256, 256, 0, stream>>>(attn_out, wo_bf, bo, (float*)d_out);
}

// Round 13
// 132.272 us; speedup vs baseline: 1.0152x; 1.0152x over previous
//
#include <hip/hip_runtime.h>
#include <cstdint>
#include <cstddef>
#include <cmath>

// ---------------------------------------------------------------------------
// MultiHeadAttention (B=2, S=2048, DIM=1024, H=16, HD=64), causal + RoPE.
// R13 = R12 with attn KVBLK 64->128: 17 (not 33) kv-iterations per pair-block
// amortizes the per-iteration fixed overhead (2 barriers + 4 shuffles +
// ballot + vmcnt wait) that R12 showed to dominate (VALU 49 / MFMA 11 / HBM 4
// — nothing saturated). K tile [128kv][64d], V tile [64d][128kv], P rows
// 256B; same verified XOR involutions, vmcnt 4->8. All other kernels
// byte-identical to R12 (passing).
// ---------------------------------------------------------------------------

typedef __bf16 bf16_t;
typedef __bf16 bf16x8 __attribute__((ext_vector_type(8)));
typedef __bf16 bf16x4 __attribute__((ext_vector_type(4)));
typedef float  f32x4  __attribute__((ext_vector_type(4)));

#define DEVFN __device__ __forceinline__

static constexpr int Bn  = 2;
static constexpr int S   = 2048;
static constexpr int DIM = 1024;
static constexpr int NH  = 16;
static constexpr int HD  = 64;
static constexpr int Mrows = Bn * S;        // 4096

DEVFN f32x4 mfma16(bf16x8 a, bf16x8 b, f32x4 c) {
  return __builtin_amdgcn_mfma_f32_16x16x32_bf16(a, b, c, 0, 0, 0);
}

DEVFN void gl_lds16(const bf16_t* g, bf16_t* l) {
  __builtin_amdgcn_global_load_lds(
      (const __attribute__((address_space(1))) unsigned*)g,
      (__attribute__((address_space(3))) unsigned*)l, 16, 0, 0);
}

DEVFN float fast_exp2(float x) { return exp2f(x); }  // -> v_exp_f32

// ---------------------------------------------------------------------------
// One launch: all fp32->bf16 converts + rope table.
__global__ __launch_bounds__(256) void k_prep(
    const float* __restrict__ x, const float* __restrict__ wq,
    const float* __restrict__ wk, const float* __restrict__ wv,
    const float* __restrict__ wo, bf16_t* __restrict__ xb,
    bf16_t* __restrict__ wqb, bf16_t* __restrict__ wkb,
    bf16_t* __restrict__ wvb, bf16_t* __restrict__ wob,
    float2* __restrict__ tab) {
  const int bid = blockIdx.x;
  if (bid < 8192) {
    const float* src;
    bf16_t* dst;
    size_t base;
    if (bid < 4096) {
      src = x; dst = xb; base = (size_t)bid << 10;
    } else {
      int wsel = (bid - 4096) >> 10;
      src = wsel == 0 ? wq : wsel == 1 ? wk : wsel == 2 ? wv : wo;
      dst = wsel == 0 ? wqb : wsel == 1 ? wkb : wsel == 2 ? wvb : wob;
      base = (size_t)((bid - 4096) & 1023) << 10;
    }
    size_t i = base + (size_t)threadIdx.x * 4;
    float4 v = *(const float4*)(src + i);
    bf16x4 o = { (bf16_t)v.x, (bf16_t)v.y, (bf16_t)v.z, (bf16_t)v.w };
    *(bf16x4*)(dst + i) = o;
  } else {
    int i = (bid - 8192) * 256 + threadIdx.x;  // < S*32
    int s = i >> 5, d = i & 31;
    float th = (float)s * expf((float)d * -0.2878231366f);  // ln(10000)/32
    tab[i] = make_float2(cosf(th), sinf(th));
  }
}

// ---------------------------------------------------------------------------
// in-place rope on [Mrows][DIM] bf16 (R4-proven body).
__global__ __launch_bounds__(256) void k_rope(bf16_t* __restrict__ X,
                                              const float2* __restrict__ tab,
                                              float scale) {
  int i = blockIdx.x * 256 + threadIdx.x;   // chunk of 8 elems
  int row = i >> 7;
  int s = row & (S - 1);
  int dd = (i & 7) << 3;
  int p0 = dd >> 1;
  bf16x8 v = *(bf16x8*)(X + (size_t)i * 8);
  bf16x8 o;
#pragma unroll
  for (int j = 0; j < 4; ++j) {
    float x1 = (float)v[2 * j], x2 = (float)v[2 * j + 1];
    float2 cs = tab[s * 32 + p0 + j];
    o[2 * j]     = (bf16_t)((x1 * cs.x - x2 * cs.y) * scale);
    o[2 * j + 1] = (bf16_t)((x1 * cs.y + x2 * cs.x) * scale);
  }
  *(bf16x8*)(X + (size_t)i * 8) = o;
}

// V [b][s][h][d] -> VT [b*h][d][s] (R4-proven body).
__global__ __launch_bounds__(256) void k_trans(const bf16_t* __restrict__ Vin,
                                               bf16_t* __restrict__ VT) {
  __shared__ __align__(16) bf16_t tile[64][72];
  int s0 = blockIdx.x * 64, bh = blockIdx.y;
  int b = bh >> 4, h = bh & 15;
  int t = threadIdx.x;
#pragma unroll
  for (int it = 0; it < 2; ++it) {
    int sl = (t >> 3) + it * 32, d0 = (t & 7) << 3;
    *(bf16x8*)&tile[sl][d0] =
        *(const bf16x8*)(Vin + (size_t)(b * S + s0 + sl) * DIM + h * HD + d0);
  }
  __syncthreads();
  int d = t >> 2, c0 = (t & 3) * 16;
  bf16_t buf[16];
#pragma unroll
  for (int j = 0; j < 16; ++j) buf[j] = tile[c0 + j][d];
  bf16_t* op = VT + ((size_t)bh * HD + d) * S + s0 + c0;
  *(bf16x8*)op = *(bf16x8*)&buf[0];
  *(bf16x8*)(op + 8) = *(bf16x8*)&buf[8];
}

// ---------------------------------------------------------------------------
// GEMM staging, BK=64 tile [128 rows][64 k] per matrix. Source pre-swizzled
// j=((c&7)^(row&7))*8, LDS dest linear; read back with byte-XOR ((row&7)<<4).
DEVFN void stage64(const bf16_t* __restrict__ A, const bf16_t* __restrict__ Bw,
                   bf16_t* Al, bf16_t* Bl, int m0, int n0, int k0, int t,
                   int w) {
#pragma unroll
  for (int ld = 0; ld < 4; ++ld) {
    int c = t + ld * 256;
    int row = c >> 3;
    int j = ((c & 7) ^ (row & 7)) << 3;
    bf16_t* dstA = Al + (size_t)(w * 64 + ld * 256) * 8;
    bf16_t* dstB = Bl + (size_t)(w * 64 + ld * 256) * 8;
    gl_lds16(A + (size_t)(m0 + row) * DIM + k0 + j, dstA);
    gl_lds16(Bw + (size_t)(n0 + row) * DIM + k0 + j, dstB);
  }
}

// ---------------------------------------------------------------------------
// Fused QKV NT GEMM: M=4096, N=3072 (wq|wk|wv contiguous), K=1024. 128x128
// tile, BK=64 (16 iters). 768 blocks, XCD rectangle swizzle. Plain bias
// epilogue -> q_lin/k_lin/v_lin.
__global__ __launch_bounds__(256) void k_gemm_qkv(
    const bf16_t* __restrict__ A, const bf16_t* __restrict__ Wall,
    const float* __restrict__ c0, const float* __restrict__ c1,
    const float* __restrict__ c2, bf16_t* __restrict__ Oq,
    bf16_t* __restrict__ Ok, bf16_t* __restrict__ Ov_) {
  __shared__ __align__(16) bf16_t Al[128 * 64];
  __shared__ __align__(16) bf16_t Bl[128 * 64];
  const int t = threadIdx.x, w = t >> 6, l = t & 63;
  const int lr = l & 15, lc = l >> 4;
  const int lid = blockIdx.x;
  const int xcd = lid & 7, s = lid >> 3;          // s in [0,96)
  const int my = ((xcd >> 1) << 3) + (s & 7);     // [0,32)
  const int nx = (xcd & 1) * 12 + (s >> 3);       // [0,24)
  const int m0 = my * 128, n0g = nx * 128;
  const int z = n0g >> 10, n0l = n0g & 1023;
  const int wr = w >> 1, wc = w & 1;
  f32x4 acc[4][4] = {};

  for (int k0 = 0; k0 < DIM; k0 += 64) {
    __syncthreads();
    stage64(A, Wall, Al, Bl, m0, n0g, k0, t, w);
    asm volatile("s_waitcnt vmcnt(0)" ::: "memory");  // belt-and-braces drain
    __syncthreads();
    bf16x8 af[2][4], bfr[2][4];
#pragma unroll
    for (int ks = 0; ks < 2; ++ks) {
#pragma unroll
      for (int mi = 0; mi < 4; ++mi) {
        int row = wr * 64 + mi * 16 + lr;
        int off = ((ks * 4 + lc) << 4) ^ ((row & 7) << 4);
        af[ks][mi] = *(const bf16x8*)((const char*)Al + row * 128 + off);
      }
#pragma unroll
      for (int ni = 0; ni < 4; ++ni) {
        int row = wc * 64 + ni * 16 + lr;
        int off = ((ks * 4 + lc) << 4) ^ ((row & 7) << 4);
        bfr[ks][ni] = *(const bf16x8*)((const char*)Bl + row * 128 + off);
      }
    }
    __builtin_amdgcn_s_setprio(1);
#pragma unroll
    for (int ks = 0; ks < 2; ++ks)
#pragma unroll
      for (int mi = 0; mi < 4; ++mi)
#pragma unroll
        for (int ni = 0; ni < 4; ++ni)
          acc[mi][ni] = mfma16(af[ks][mi], bfr[ks][ni], acc[mi][ni]);
    __builtin_amdgcn_s_setprio(0);
  }

  bf16_t* Ov = z == 0 ? Oq : (z == 1 ? Ok : Ov_);
  const float* bias = z == 0 ? c0 : (z == 1 ? c1 : c2);
#pragma unroll
  for (int ni = 0; ni < 4; ++ni) {
    const int col = n0l + wc * 64 + ni * 16 + lr;
    const float bv = bias[col];
#pragma unroll
    for (int mi = 0; mi < 4; ++mi)
#pragma unroll
      for (int r = 0; r < 4; ++r) {
        int row = m0 + wr * 64 + mi * 16 + lc * 4 + r;
        Ov[(size_t)row * DIM + col] = (bf16_t)(acc[mi][ni][r] + bv);
      }
  }
}

// ---------------------------------------------------------------------------
// Out projection: M=4096, N=1024, K=1024. 256 blocks, same BK=64 loop.
__global__ __launch_bounds__(256) void k_gemm_out(
    const bf16_t* __restrict__ A, const bf16_t* __restrict__ Bw,
    const float* __restrict__ bias, float* __restrict__ Ov) {
  __shared__ __align__(16) bf16_t Al[128 * 64];
  __shared__ __align__(16) bf16_t Bl[128 * 64];
  const int t = threadIdx.x, w = t >> 6, l = t & 63;
  const int lr = l & 15, lc = l >> 4;
  const int lid = blockIdx.x;
  const int xcd = lid & 7, s = lid >> 3;          // s in [0,32)
  const int my = ((xcd >> 1) << 3) + (s & 7);     // [0,32)
  const int nx = (xcd & 1) * 4 + (s >> 3);        // [0,8)
  const int m0 = my * 128, n0 = nx * 128;
  const int wr = w >> 1, wc = w & 1;
  f32x4 acc[4][4] = {};

  for (int k0 = 0; k0 < DIM; k0 += 64) {
    __syncthreads();
    stage64(A, Bw, Al, Bl, m0, n0, k0, t, w);
    asm volatile("s_waitcnt vmcnt(0)" ::: "memory");  // belt-and-braces drain
    __syncthreads();
    bf16x8 af[2][4], bfr[2][4];
#pragma unroll
    for (int ks = 0; ks < 2; ++ks) {
#pragma unroll
      for (int mi = 0; mi < 4; ++mi) {
        int row = wr * 64 + mi * 16 + lr;
        int off = ((ks * 4 + lc) << 4) ^ ((row & 7) << 4);
        af[ks][mi] = *(const bf16x8*)((const char*)Al + row * 128 + off);
      }
#pragma unroll
      for (int ni = 0; ni < 4; ++ni) {
        int row = wc * 64 + ni * 16 + lr;
        int off = ((ks * 4 + lc) << 4) ^ ((row & 7) << 4);
        bfr[ks][ni] = *(const bf16x8*)((const char*)Bl + row * 128 + off);
      }
    }
    __builtin_amdgcn_s_setprio(1);
#pragma unroll
    for (int ks = 0; ks < 2; ++ks)
#pragma unroll
      for (int mi = 0; mi < 4; ++mi)
#pragma unroll
        for (int ni = 0; ni < 4; ++ni)
          acc[mi][ni] = mfma16(af[ks][mi], bfr[ks][ni], acc[mi][ni]);
    __builtin_amdgcn_s_setprio(0);
  }

#pragma unroll
  for (int ni = 0; ni < 4; ++ni) {
    int col = n0 + wc * 64 + ni * 16 + lr;
    float bv = bias[col];
#pragma unroll
    for (int mi = 0; mi < 4; ++mi)
#pragma unroll
      for (int r = 0; r < 4; ++r) {
        int row = m0 + wr * 64 + mi * 16 + lc * 4 + r;
        Ov[(size_t)row * DIM + col] = acc[mi][ni][r] + bv;
      }
  }
}

// ---------------------------------------------------------------------------
// Causal flash attention, KVBLK=128.
// Paired q-tiles (a, 31-a): uniform 17 kv-iterations per block.
// K tile [128 kv][64 d] (8 16B-chunks/row), V tile [64 d][128 kv] (16
// chunks/row), both staged via global_load_lds with pre-swizzled source
// chunk (involution: chunk ^= row&7), read back with the matching byte-XOR.
// Swapped QK^T (s = mfma(K,Q)): lane (lr,lc) holds S'[q=w*16+lr]
// [k=ni*16+lc*4+r], ni 0..7, in log2 units. Defer-max THR=8. P rows 256B.
// vmcnt(8) counted waits (8 loads per stage). XCD remap: 4 heads/XCD.
DEVFN void stage_kv(const bf16_t* __restrict__ Kc,
                    const bf16_t* __restrict__ VT, bf16_t* Kb, bf16_t* Vb,
                    int b, int bh, int h, int k0, int tid, int w) {
#pragma unroll
  for (int ld = 0; ld < 4; ++ld) {
    int c = tid + ld * 256;                    // chunk id 0..1023
    bf16_t* dstK = Kb + (size_t)(w * 64 + ld * 256) * 8;
    bf16_t* dstV = Vb + (size_t)(w * 64 + ld * 256) * 8;
    // K: 128 rows x 8 chunks
    int krow = c >> 3;
    int kj = ((c & 7) ^ (krow & 7)) << 3;
    gl_lds16(Kc + (size_t)(b * S + k0 + krow) * DIM + h * HD + kj, dstK);
    // V: 64 rows x 16 chunks
    int vrow = c >> 4;
    int vj = ((c & 15) ^ (vrow & 7)) << 3;
    gl_lds16(VT + ((size_t)bh * HD + vrow) * S + k0 + vj, dstV);
  }
}

__global__ __launch_bounds__(256) void k_attn(const bf16_t* __restrict__ Q,
                                              const bf16_t* __restrict__ Kc,
                                              const bf16_t* __restrict__ VT,
                                              bf16_t* __restrict__ O) {
  __shared__ __align__(16) bf16_t Kl[2][128 * 64];
  __shared__ __align__(16) bf16_t Vl[2][64 * 128];
  __shared__ __align__(16) bf16_t Pl[4][16 * 128];
  const int tid = threadIdx.x, w = tid >> 6, l = tid & 63;
  const int lr = l & 15, lc = l >> 4;
  const int lid = blockIdx.x + (blockIdx.y << 4);
  const int xcd = lid & 7, slot = lid >> 3;
  const int bh = xcd * 4 + (slot >> 4);
  const int a = slot & 15;
  const int b = bh >> 4, h = bh & 15;
  char* Pw = (char*)&Pl[w][0];

#pragma unroll 1
  for (int pi = 0; pi < 2; ++pi) {
    const int tile = (pi == 0) ? a : 31 - a;
    const int q0 = tile * 64;
    const int nt = (tile >> 1) + 1;            // ceil((tile+1)/2) 128-kv tiles

    bf16x8 qf[2];
    {
      const bf16_t* qp =
          Q + (size_t)(b * S + q0 + w * 16 + lr) * DIM + h * HD + lc * 8;
      qf[0] = *(const bf16x8*)qp;
      qf[1] = *(const bf16x8*)(qp + 32);
    }
    f32x4 o[4] = {};
    float m_run = -INFINITY;
    float rowsum = 0.f;

    // prologue: stage tile 0
    stage_kv(Kc, VT, &Kl[0][0], &Vl[0][0], b, bh, h, 0, tid, w);

#pragma unroll 1
    for (int it = 0; it < nt; ++it) {
      const int cur = it & 1;
      const bf16_t* Kb = &Kl[cur][0];
      const bf16_t* Vb = &Vl[cur][0];
      if (it + 1 < nt) {
        stage_kv(Kc, VT, &Kl[cur ^ 1][0], &Vl[cur ^ 1][0], b, bh, h,
                 (it + 1) * 128, tid, w);
        asm volatile("s_waitcnt vmcnt(8)" ::: "memory");
      } else {
        asm volatile("s_waitcnt vmcnt(0)" ::: "memory");
      }
      __builtin_amdgcn_s_barrier();
      __builtin_amdgcn_sched_barrier(0);

      // swapped QK^T: lane (lr,lc) holds S'[q=w*16+lr][k=ni*16+lc*4+r]
      f32x4 s[8];
#pragma unroll
      for (int ni = 0; ni < 8; ++ni) s[ni] = f32x4{0.f, 0.f, 0.f, 0.f};
      __builtin_amdgcn_s_setprio(1);
#pragma unroll
      for (int ks = 0; ks < 2; ++ks) {
#pragma unroll
        for (int ni = 0; ni < 8; ++ni) {
          int row = ni * 16 + lr;
          int off = (ks * 64 + lc * 16) ^ ((row & 7) << 4);
          bf16x8 kf = *(const bf16x8*)((const char*)Kb + row * 128 + off);
          s[ni] = mfma16(kf, qf[ks], s[ni]);
        }
      }
      __builtin_amdgcn_s_setprio(0);

      if (it == nt - 1) {  // diagonal (and tail-masked) tile
        const int qloc = q0 - (nt - 1) * 128 + w * 16 + lr;
#pragma unroll
        for (int ni = 0; ni < 8; ++ni)
#pragma unroll
          for (int r = 0; r < 4; ++r)
            if (ni * 16 + lc * 4 + r > qloc) s[ni][r] = -INFINITY;
      }

      // row max: paired tree, then 2 cross-lane reduces
      float mm[8];
#pragma unroll
      for (int ni = 0; ni < 8; ++ni)
        mm[ni] = fmaxf(fmaxf(s[ni][0], s[ni][1]), fmaxf(s[ni][2], s[ni][3]));
      float pm = fmaxf(fmaxf(fmaxf(mm[0], mm[1]), fmaxf(mm[2], mm[3])),
                       fmaxf(fmaxf(mm[4], mm[5]), fmaxf(mm[6], mm[7])));
      pm = fmaxf(pm, __shfl_xor(pm, 16));
      pm = fmaxf(pm, __shfl_xor(pm, 32));

      // defer-max (log2 units): rescale only if max grew past 8 (P <= 2^8)
      if (__ballot(pm > m_run + 8.f)) {
        float mn = fmaxf(m_run, pm);
        float alpha = fast_exp2(m_run - mn);
        m_run = mn;
        rowsum *= alpha;
#pragma unroll
        for (int r = 0; r < 4; ++r) {
          float aq = __shfl(alpha, lc * 4 + r);
#pragma unroll
          for (int ni = 0; ni < 4; ++ni) o[ni][r] *= aq;
        }
      }

      // P = exp2(s - m_run); in-lane partial sum; pack to LDS as b64
      float rs = 0.f;
#pragma unroll
      for (int ni = 0; ni < 8; ++ni) {
        float p0 = fast_exp2(s[ni][0] - m_run);
        float p1 = fast_exp2(s[ni][1] - m_run);
        float p2 = fast_exp2(s[ni][2] - m_run);
        float p3 = fast_exp2(s[ni][3] - m_run);
        rs += (p0 + p1) + (p2 + p3);
        bf16x4 pb = { (bf16_t)p0, (bf16_t)p1, (bf16_t)p2, (bf16_t)p3 };
        *(bf16x4*)(Pw + (lr * 256 + ((ni * 32 + lc * 8) ^ ((lr & 7) << 4)))) =
            pb;
      }
      rs += __shfl_xor(rs, 16);
      rs += __shfl_xor(rs, 32);
      rowsum += rs;

      // PV: o[ni] += P(16x128) * V(128x64)
      __builtin_amdgcn_s_setprio(1);
#pragma unroll
      for (int ks = 0; ks < 4; ++ks) {
        int off = ks * 64 + lc * 16;
        bf16x8 pa =
            *(const bf16x8*)(Pw + lr * 256 + (off ^ ((lr & 7) << 4)));
#pragma unroll
        for (int ni = 0; ni < 4; ++ni) {
          int vrow = ni * 16 + lr;
          bf16x8 vb = *(const bf16x8*)((const char*)Vb + vrow * 256 +
                                       (off ^ ((vrow & 7) << 4)));
          o[ni] = mfma16(pa, vb, o[ni]);
        }
      }
      __builtin_amdgcn_s_setprio(0);

      __builtin_amdgcn_s_barrier();  // compute done before next stage overwrite
    }

    // normalize + store. o[ni]: q = q0 + w*16 + lc*4 + r, d = ni*16 + lr
    float inv[4];
#pragma unroll
    for (int r = 0; r < 4; ++r) inv[r] = 1.0f / __shfl(rowsum, lc * 4 + r);
#pragma unroll
    for (int ni = 0; ni < 4; ++ni)
#pragma unroll
      for (int r = 0; r < 4; ++r) {
        int qr = q0 + w * 16 + lc * 4 + r;
        float v = o[ni][r] * inv[r];
        O[(size_t)(b * S + qr) * DIM + h * HD + ni * 16 + lr] = (bf16_t)v;
      }
  }
}

// ---------------------------------------------------------------------------
extern "C" void kernel_launch(void* const* d_in, const int* in_sizes, int n_in,
                              void* d_out, int out_size, void* d_ws,
                              size_t ws_size, hipStream_t stream) {
  const float* x  = (const float*)d_in[0];
  const float* wq = (const float*)d_in[1];
  const float* bq = (const float*)d_in[2];
  const float* wk = (const float*)d_in[3];
  const float* bk = (const float*)d_in[4];
  const float* wv = (const float*)d_in[5];
  const float* bv = (const float*)d_in[6];
  const float* wo = (const float*)d_in[7];
  const float* bo = (const float*)d_in[8];

  const size_t MD = (size_t)Mrows * DIM;   // 4194304
  const size_t WD = (size_t)DIM * DIM;     // 1048576
  bf16_t* W = (bf16_t*)d_ws;
  bf16_t* x_bf  = W;
  bf16_t* wq_bf = x_bf + MD;               // wq|wk|wv contiguous = [3072][1024]
  bf16_t* wk_bf = wq_bf + WD;
  bf16_t* wv_bf = wk_bf + WD;
  bf16_t* wo_bf = wv_bf + WD;
  bf16_t* q_lin = wo_bf + WD;
  bf16_t* k_lin = q_lin + MD;
  bf16_t* v_lin = k_lin + MD;
  bf16_t* vT    = v_lin + MD;
  float2* tab   = (float2*)(vT + MD);
  bf16_t* attn_out = x_bf;  // x_bf dead after k_gemm_qkv; rewritten by k_prep
                            // every call -> no cross-call state dependency

  k_prep<<<8448, 256, 0, stream>>>(x, wq, wk, wv, wo, x_bf, wq_bf, wk_bf,
                                   wv_bf, wo_bf, tab);

  k_gemm_qkv<<<768, 256, 0, stream>>>(x_bf, wq_bf, bq, bk, bv, q_lin, k_lin,
                                      v_lin);

  // Q scale folds 1/sqrt(64) AND log2(e) -> QK^T scores land in log2 units.
  k_rope<<<2048, 256, 0, stream>>>(q_lin, tab, 0.125f * 1.4426950408889634f);
  k_rope<<<2048, 256, 0, stream>>>(k_lin, tab, 1.0f);
  k_trans<<<dim3(S / 64, Bn * NH), 256, 0, stream>>>(v_lin, vT);

  k_attn<<<dim3(16, Bn * NH), 256, 0, stream>>>(q_lin, k_lin, vT, attn_out);

  k_gemm_out<<<256, 256, 0, stream>>>(attn_out, wo_bf, bo, (float*)d_out);
}

// Round 14
// 129.622 us; speedup vs baseline: 1.0359x; 1.0204x over previous
//
#include <hip/hip_runtime.h>
#include <cstdint>
#include <cstddef>
#include <cmath>

// ---------------------------------------------------------------------------
// MultiHeadAttention (B=2, S=2048, DIM=1024, H=16, HD=64), causal + RoPE.
// R14: attn concurrency fix. R13 showed per-iteration CHAIN LATENCY bound at
// 2 blocks/CU (4060 cyc/block-iter vs ~900 issue work). Revert KVBLK to 64
// (LDS 40KB -> 4 blocks/CU), un-pair q-tiles (grid 1024, 1 tile/block),
// balance via descending-workload dispatch order (big tiles first, scheduler
// backfills). Attn body = R12's passing body. All other kernels = R13.
// ---------------------------------------------------------------------------

typedef __bf16 bf16_t;
typedef __bf16 bf16x8 __attribute__((ext_vector_type(8)));
typedef __bf16 bf16x4 __attribute__((ext_vector_type(4)));
typedef float  f32x4  __attribute__((ext_vector_type(4)));

#define DEVFN __device__ __forceinline__

static constexpr int Bn  = 2;
static constexpr int S   = 2048;
static constexpr int DIM = 1024;
static constexpr int NH  = 16;
static constexpr int HD  = 64;
static constexpr int Mrows = Bn * S;        // 4096

DEVFN f32x4 mfma16(bf16x8 a, bf16x8 b, f32x4 c) {
  return __builtin_amdgcn_mfma_f32_16x16x32_bf16(a, b, c, 0, 0, 0);
}

DEVFN void gl_lds16(const bf16_t* g, bf16_t* l) {
  __builtin_amdgcn_global_load_lds(
      (const __attribute__((address_space(1))) unsigned*)g,
      (__attribute__((address_space(3))) unsigned*)l, 16, 0, 0);
}

DEVFN float fast_exp2(float x) { return exp2f(x); }  // -> v_exp_f32

// ---------------------------------------------------------------------------
// One launch: all fp32->bf16 converts + rope table.
__global__ __launch_bounds__(256) void k_prep(
    const float* __restrict__ x, const float* __restrict__ wq,
    const float* __restrict__ wk, const float* __restrict__ wv,
    const float* __restrict__ wo, bf16_t* __restrict__ xb,
    bf16_t* __restrict__ wqb, bf16_t* __restrict__ wkb,
    bf16_t* __restrict__ wvb, bf16_t* __restrict__ wob,
    float2* __restrict__ tab) {
  const int bid = blockIdx.x;
  if (bid < 8192) {
    const float* src;
    bf16_t* dst;
    size_t base;
    if (bid < 4096) {
      src = x; dst = xb; base = (size_t)bid << 10;
    } else {
      int wsel = (bid - 4096) >> 10;
      src = wsel == 0 ? wq : wsel == 1 ? wk : wsel == 2 ? wv : wo;
      dst = wsel == 0 ? wqb : wsel == 1 ? wkb : wsel == 2 ? wvb : wob;
      base = (size_t)((bid - 4096) & 1023) << 10;
    }
    size_t i = base + (size_t)threadIdx.x * 4;
    float4 v = *(const float4*)(src + i);
    bf16x4 o = { (bf16_t)v.x, (bf16_t)v.y, (bf16_t)v.z, (bf16_t)v.w };
    *(bf16x4*)(dst + i) = o;
  } else {
    int i = (bid - 8192) * 256 + threadIdx.x;  // < S*32
    int s = i >> 5, d = i & 31;
    float th = (float)s * expf((float)d * -0.2878231366f);  // ln(10000)/32
    tab[i] = make_float2(cosf(th), sinf(th));
  }
}

// ---------------------------------------------------------------------------
// in-place rope on [Mrows][DIM] bf16 (R4-proven body).
__global__ __launch_bounds__(256) void k_rope(bf16_t* __restrict__ X,
                                              const float2* __restrict__ tab,
                                              float scale) {
  int i = blockIdx.x * 256 + threadIdx.x;   // chunk of 8 elems
  int row = i >> 7;
  int s = row & (S - 1);
  int dd = (i & 7) << 3;
  int p0 = dd >> 1;
  bf16x8 v = *(bf16x8*)(X + (size_t)i * 8);
  bf16x8 o;
#pragma unroll
  for (int j = 0; j < 4; ++j) {
    float x1 = (float)v[2 * j], x2 = (float)v[2 * j + 1];
    float2 cs = tab[s * 32 + p0 + j];
    o[2 * j]     = (bf16_t)((x1 * cs.x - x2 * cs.y) * scale);
    o[2 * j + 1] = (bf16_t)((x1 * cs.y + x2 * cs.x) * scale);
  }
  *(bf16x8*)(X + (size_t)i * 8) = o;
}

// V [b][s][h][d] -> VT [b*h][d][s] (R4-proven body).
__global__ __launch_bounds__(256) void k_trans(const bf16_t* __restrict__ Vin,
                                               bf16_t* __restrict__ VT) {
  __shared__ __align__(16) bf16_t tile[64][72];
  int s0 = blockIdx.x * 64, bh = blockIdx.y;
  int b = bh >> 4, h = bh & 15;
  int t = threadIdx.x;
#pragma unroll
  for (int it = 0; it < 2; ++it) {
    int sl = (t >> 3) + it * 32, d0 = (t & 7) << 3;
    *(bf16x8*)&tile[sl][d0] =
        *(const bf16x8*)(Vin + (size_t)(b * S + s0 + sl) * DIM + h * HD + d0);
  }
  __syncthreads();
  int d = t >> 2, c0 = (t & 3) * 16;
  bf16_t buf[16];
#pragma unroll
  for (int j = 0; j < 16; ++j) buf[j] = tile[c0 + j][d];
  bf16_t* op = VT + ((size_t)bh * HD + d) * S + s0 + c0;
  *(bf16x8*)op = *(bf16x8*)&buf[0];
  *(bf16x8*)(op + 8) = *(bf16x8*)&buf[8];
}

// ---------------------------------------------------------------------------
// GEMM staging, BK=64 tile [128 rows][64 k] per matrix. Source pre-swizzled
// j=((c&7)^(row&7))*8, LDS dest linear; read back with byte-XOR ((row&7)<<4).
DEVFN void stage64(const bf16_t* __restrict__ A, const bf16_t* __restrict__ Bw,
                   bf16_t* Al, bf16_t* Bl, int m0, int n0, int k0, int t,
                   int w) {
#pragma unroll
  for (int ld = 0; ld < 4; ++ld) {
    int c = t + ld * 256;
    int row = c >> 3;
    int j = ((c & 7) ^ (row & 7)) << 3;
    bf16_t* dstA = Al + (size_t)(w * 64 + ld * 256) * 8;
    bf16_t* dstB = Bl + (size_t)(w * 64 + ld * 256) * 8;
    gl_lds16(A + (size_t)(m0 + row) * DIM + k0 + j, dstA);
    gl_lds16(Bw + (size_t)(n0 + row) * DIM + k0 + j, dstB);
  }
}

// ---------------------------------------------------------------------------
// Fused QKV NT GEMM: M=4096, N=3072 (wq|wk|wv contiguous), K=1024. 128x128
// tile, BK=64 (16 iters). 768 blocks, XCD rectangle swizzle. Plain bias
// epilogue -> q_lin/k_lin/v_lin.
__global__ __launch_bounds__(256) void k_gemm_qkv(
    const bf16_t* __restrict__ A, const bf16_t* __restrict__ Wall,
    const float* __restrict__ c0, const float* __restrict__ c1,
    const float* __restrict__ c2, bf16_t* __restrict__ Oq,
    bf16_t* __restrict__ Ok, bf16_t* __restrict__ Ov_) {
  __shared__ __align__(16) bf16_t Al[128 * 64];
  __shared__ __align__(16) bf16_t Bl[128 * 64];
  const int t = threadIdx.x, w = t >> 6, l = t & 63;
  const int lr = l & 15, lc = l >> 4;
  const int lid = blockIdx.x;
  const int xcd = lid & 7, s = lid >> 3;          // s in [0,96)
  const int my = ((xcd >> 1) << 3) + (s & 7);     // [0,32)
  const int nx = (xcd & 1) * 12 + (s >> 3);       // [0,24)
  const int m0 = my * 128, n0g = nx * 128;
  const int z = n0g >> 10, n0l = n0g & 1023;
  const int wr = w >> 1, wc = w & 1;
  f32x4 acc[4][4] = {};

  for (int k0 = 0; k0 < DIM; k0 += 64) {
    __syncthreads();
    stage64(A, Wall, Al, Bl, m0, n0g, k0, t, w);
    asm volatile("s_waitcnt vmcnt(0)" ::: "memory");  // belt-and-braces drain
    __syncthreads();
    bf16x8 af[2][4], bfr[2][4];
#pragma unroll
    for (int ks = 0; ks < 2; ++ks) {
#pragma unroll
      for (int mi = 0; mi < 4; ++mi) {
        int row = wr * 64 + mi * 16 + lr;
        int off = ((ks * 4 + lc) << 4) ^ ((row & 7) << 4);
        af[ks][mi] = *(const bf16x8*)((const char*)Al + row * 128 + off);
      }
#pragma unroll
      for (int ni = 0; ni < 4; ++ni) {
        int row = wc * 64 + ni * 16 + lr;
        int off = ((ks * 4 + lc) << 4) ^ ((row & 7) << 4);
        bfr[ks][ni] = *(const bf16x8*)((const char*)Bl + row * 128 + off);
      }
    }
    __builtin_amdgcn_s_setprio(1);
#pragma unroll
    for (int ks = 0; ks < 2; ++ks)
#pragma unroll
      for (int mi = 0; mi < 4; ++mi)
#pragma unroll
        for (int ni = 0; ni < 4; ++ni)
          acc[mi][ni] = mfma16(af[ks][mi], bfr[ks][ni], acc[mi][ni]);
    __builtin_amdgcn_s_setprio(0);
  }

  bf16_t* Ov = z == 0 ? Oq : (z == 1 ? Ok : Ov_);
  const float* bias = z == 0 ? c0 : (z == 1 ? c1 : c2);
#pragma unroll
  for (int ni = 0; ni < 4; ++ni) {
    const int col = n0l + wc * 64 + ni * 16 + lr;
    const float bv = bias[col];
#pragma unroll
    for (int mi = 0; mi < 4; ++mi)
#pragma unroll
      for (int r = 0; r < 4; ++r) {
        int row = m0 + wr * 64 + mi * 16 + lc * 4 + r;
        Ov[(size_t)row * DIM + col] = (bf16_t)(acc[mi][ni][r] + bv);
      }
  }
}

// ---------------------------------------------------------------------------
// Out projection: M=4096, N=1024, K=1024. 256 blocks, same BK=64 loop.
__global__ __launch_bounds__(256) void k_gemm_out(
    const bf16_t* __restrict__ A, const bf16_t* __restrict__ Bw,
    const float* __restrict__ bias, float* __restrict__ Ov) {
  __shared__ __align__(16) bf16_t Al[128 * 64];
  __shared__ __align__(16) bf16_t Bl[128 * 64];
  const int t = threadIdx.x, w = t >> 6, l = t & 63;
  const int lr = l & 15, lc = l >> 4;
  const int lid = blockIdx.x;
  const int xcd = lid & 7, s = lid >> 3;          // s in [0,32)
  const int my = ((xcd >> 1) << 3) + (s & 7);     // [0,32)
  const int nx = (xcd & 1) * 4 + (s >> 3);        // [0,8)
  const int m0 = my * 128, n0 = nx * 128;
  const int wr = w >> 1, wc = w & 1;
  f32x4 acc[4][4] = {};

  for (int k0 = 0; k0 < DIM; k0 += 64) {
    __syncthreads();
    stage64(A, Bw, Al, Bl, m0, n0, k0, t, w);
    asm volatile("s_waitcnt vmcnt(0)" ::: "memory");  // belt-and-braces drain
    __syncthreads();
    bf16x8 af[2][4], bfr[2][4];
#pragma unroll
    for (int ks = 0; ks < 2; ++ks) {
#pragma unroll
      for (int mi = 0; mi < 4; ++mi) {
        int row = wr * 64 + mi * 16 + lr;
        int off = ((ks * 4 + lc) << 4) ^ ((row & 7) << 4);
        af[ks][mi] = *(const bf16x8*)((const char*)Al + row * 128 + off);
      }
#pragma unroll
      for (int ni = 0; ni < 4; ++ni) {
        int row = wc * 64 + ni * 16 + lr;
        int off = ((ks * 4 + lc) << 4) ^ ((row & 7) << 4);
        bfr[ks][ni] = *(const bf16x8*)((const char*)Bl + row * 128 + off);
      }
    }
    __builtin_amdgcn_s_setprio(1);
#pragma unroll
    for (int ks = 0; ks < 2; ++ks)
#pragma unroll
      for (int mi = 0; mi < 4; ++mi)
#pragma unroll
        for (int ni = 0; ni < 4; ++ni)
          acc[mi][ni] = mfma16(af[ks][mi], bfr[ks][ni], acc[mi][ni]);
    __builtin_amdgcn_s_setprio(0);
  }

#pragma unroll
  for (int ni = 0; ni < 4; ++ni) {
    int col = n0 + wc * 64 + ni * 16 + lr;
    float bv = bias[col];
#pragma unroll
    for (int mi = 0; mi < 4; ++mi)
#pragma unroll
      for (int r = 0; r < 4; ++r) {
        int row = m0 + wr * 64 + mi * 16 + lc * 4 + r;
        Ov[(size_t)row * DIM + col] = acc[mi][ni][r] + bv;
      }
  }
}

// ---------------------------------------------------------------------------
// Causal flash attention, R14: KVBLK=64, ONE q-tile per block, grid 1024,
// descending-workload dispatch (t_ord=0 -> tile 31), 4 blocks/CU (40KB LDS).
// Body identical to R12's (passing). XCD remap keeps 4 heads per XCD.
DEVFN void stage_kv(const bf16_t* __restrict__ Kc,
                    const bf16_t* __restrict__ VT, bf16_t* Kb, bf16_t* Vb,
                    int b, int bh, int h, int k0, int tid, int w) {
#pragma unroll
  for (int ld = 0; ld < 2; ++ld) {
    int c = tid + ld * 256;
    int row = c >> 3;
    int j = ((c & 7) ^ (row & 7)) << 3;  // pre-swizzled source chunk
    bf16_t* dstK = Kb + (size_t)(w * 64 + ld * 256) * 8;
    bf16_t* dstV = Vb + (size_t)(w * 64 + ld * 256) * 8;
    gl_lds16(Kc + (size_t)(b * S + k0 + row) * DIM + h * HD + j, dstK);
    gl_lds16(VT + ((size_t)bh * HD + row) * S + k0 + j, dstV);
  }
}

__global__ __launch_bounds__(256) void k_attn(const bf16_t* __restrict__ Q,
                                              const bf16_t* __restrict__ Kc,
                                              const bf16_t* __restrict__ VT,
                                              bf16_t* __restrict__ O) {
  __shared__ __align__(16) bf16_t Kl[2][64 * 64];
  __shared__ __align__(16) bf16_t Vl[2][64 * 64];
  __shared__ __align__(16) bf16_t Pl[4][16 * 64];
  const int tid = threadIdx.x, w = tid >> 6, l = tid & 63;
  const int lr = l & 15, lc = l >> 4;
  // lid -> (xcd, t_ord, head-in-xcd): tiles DESCENDING in dispatch order so
  // the 32-iteration blocks launch first; scheduler backfills short ones.
  const int lid = blockIdx.x;
  const int xcd = lid & 7;
  const int rest = lid >> 3;          // 0..127
  const int t_ord = rest >> 2;        // 0..31
  const int hh = rest & 3;
  const int tile = 31 - t_ord;
  const int bh = xcd * 4 + hh;
  const int b = bh >> 4, h = bh & 15;
  char* Pw = (char*)&Pl[w][0];

  const int q0 = tile * 64;
  const int nt = tile + 1;

  bf16x8 qf[2];
  {
    const bf16_t* qp =
        Q + (size_t)(b * S + q0 + w * 16 + lr) * DIM + h * HD + lc * 8;
    qf[0] = *(const bf16x8*)qp;
    qf[1] = *(const bf16x8*)(qp + 32);
  }
  f32x4 o[4] = {};
  float m_run = -INFINITY;
  float rowsum = 0.f;

  // prologue: stage tile 0
  stage_kv(Kc, VT, &Kl[0][0], &Vl[0][0], b, bh, h, 0, tid, w);

#pragma unroll 1
  for (int it = 0; it < nt; ++it) {
    const int cur = it & 1;
    const bf16_t* Kb = &Kl[cur][0];
    const bf16_t* Vb = &Vl[cur][0];
    if (it + 1 < nt) {
      stage_kv(Kc, VT, &Kl[cur ^ 1][0], &Vl[cur ^ 1][0], b, bh, h,
               (it + 1) * 64, tid, w);
      asm volatile("s_waitcnt vmcnt(4)" ::: "memory");
    } else {
      asm volatile("s_waitcnt vmcnt(0)" ::: "memory");
    }
    __builtin_amdgcn_s_barrier();
    __builtin_amdgcn_sched_barrier(0);

    // swapped QK^T: lane (lr,lc) holds S'[q=w*16+lr][k=ni*16+lc*4+r]
    f32x4 s[4] = {};
    __builtin_amdgcn_s_setprio(1);
#pragma unroll
    for (int ks = 0; ks < 2; ++ks) {
#pragma unroll
      for (int ni = 0; ni < 4; ++ni) {
        int row = ni * 16 + lr;
        int off = (ks * 64 + lc * 16) ^ ((row & 7) << 4);
        bf16x8 kf = *(const bf16x8*)((const char*)Kb + row * 128 + off);
        s[ni] = mfma16(kf, qf[ks], s[ni]);
      }
    }
    __builtin_amdgcn_s_setprio(0);

    if (it == tile) {  // diagonal tile: mask k_local > q_local
      const int qloc = w * 16 + lr;
#pragma unroll
      for (int ni = 0; ni < 4; ++ni)
#pragma unroll
        for (int r = 0; r < 4; ++r)
          if (ni * 16 + lc * 4 + r > qloc) s[ni][r] = -INFINITY;
    }

    // row max: paired tree (v_max3-friendly), then 2 cross-lane reduces
    float m01 = fmaxf(fmaxf(s[0][0], s[0][1]), fmaxf(s[0][2], s[0][3]));
    float m23 = fmaxf(fmaxf(s[1][0], s[1][1]), fmaxf(s[1][2], s[1][3]));
    float m45 = fmaxf(fmaxf(s[2][0], s[2][1]), fmaxf(s[2][2], s[2][3]));
    float m67 = fmaxf(fmaxf(s[3][0], s[3][1]), fmaxf(s[3][2], s[3][3]));
    float pm = fmaxf(fmaxf(m01, m23), fmaxf(m45, m67));
    pm = fmaxf(pm, __shfl_xor(pm, 16));
    pm = fmaxf(pm, __shfl_xor(pm, 32));

    // defer-max (log2 units): rescale only if max grew past 8 (P <= 2^8)
    if (__ballot(pm > m_run + 8.f)) {
      float mn = fmaxf(m_run, pm);
      float alpha = fast_exp2(m_run - mn);
      m_run = mn;
      rowsum *= alpha;
#pragma unroll
      for (int r = 0; r < 4; ++r) {
        float aq = __shfl(alpha, lc * 4 + r);
#pragma unroll
        for (int ni = 0; ni < 4; ++ni) o[ni][r] *= aq;
      }
    }

    // P = exp2(s - m_run); in-lane partial sum; pack to LDS as b64
    float rs = 0.f;
#pragma unroll
    for (int ni = 0; ni < 4; ++ni) {
      float p0 = fast_exp2(s[ni][0] - m_run);
      float p1 = fast_exp2(s[ni][1] - m_run);
      float p2 = fast_exp2(s[ni][2] - m_run);
      float p3 = fast_exp2(s[ni][3] - m_run);
      rs += (p0 + p1) + (p2 + p3);
      bf16x4 pb = { (bf16_t)p0, (bf16_t)p1, (bf16_t)p2, (bf16_t)p3 };
      *(bf16x4*)(Pw + (lr * 128 + ((ni * 32 + lc * 8) ^ ((lr & 7) << 4)))) =
          pb;
    }
    rs += __shfl_xor(rs, 16);
    rs += __shfl_xor(rs, 32);
    rowsum += rs;

    // PV: o[ni] += P(16x64) * V(64x64)
    __builtin_amdgcn_s_setprio(1);
#pragma unroll
    for (int ks = 0; ks < 2; ++ks) {
      int off = ks * 64 + lc * 16;
      bf16x8 pa = *(const bf16x8*)(Pw + lr * 128 + (off ^ ((lr & 7) << 4)));
#pragma unroll
      for (int ni = 0; ni < 4; ++ni) {
        int vrow = ni * 16 + lr;
        bf16x8 vb = *(const bf16x8*)((const char*)Vb + vrow * 128 +
                                     (off ^ ((vrow & 7) << 4)));
        o[ni] = mfma16(pa, vb, o[ni]);
      }
    }
    __builtin_amdgcn_s_setprio(0);

    __builtin_amdgcn_s_barrier();  // compute done before next stage overwrite
  }

  // normalize + store. o[ni]: q = q0 + w*16 + lc*4 + r, d = ni*16 + lr
  float inv[4];
#pragma unroll
  for (int r = 0; r < 4; ++r) inv[r] = 1.0f / __shfl(rowsum, lc * 4 + r);
#pragma unroll
  for (int ni = 0; ni < 4; ++ni)
#pragma unroll
    for (int r = 0; r < 4; ++r) {
      int qr = q0 + w * 16 + lc * 4 + r;
      float v = o[ni][r] * inv[r];
      O[(size_t)(b * S + qr) * DIM + h * HD + ni * 16 + lr] = (bf16_t)v;
    }
}

// ---------------------------------------------------------------------------
extern "C" void kernel_launch(void* const* d_in, const int* in_sizes, int n_in,
                              void* d_out, int out_size, void* d_ws,
                              size_t ws_size, hipStream_t stream) {
  const float* x  = (const float*)d_in[0];
  const float* wq = (const float*)d_in[1];
  const float* bq = (const float*)d_in[2];
  const float* wk = (const float*)d_in[3];
  const float* bk = (const float*)d_in[4];
  const float* wv = (const float*)d_in[5];
  const float* bv = (const float*)d_in[6];
  const float* wo = (const float*)d_in[7];
  const float* bo = (const float*)d_in[8];

  const size_t MD = (size_t)Mrows * DIM;   // 4194304
  const size_t WD = (size_t)DIM * DIM;     // 1048576
  bf16_t* W = (bf16_t*)d_ws;
  bf16_t* x_bf  = W;
  bf16_t* wq_bf = x_bf + MD;               // wq|wk|wv contiguous = [3072][1024]
  bf16_t* wk_bf = wq_bf + WD;
  bf16_t* wv_bf = wk_bf + WD;
  bf16_t* wo_bf = wv_bf + WD;
  bf16_t* q_lin = wo_bf + WD;
  bf16_t* k_lin = q_lin + MD;
  bf16_t* v_lin = k_lin + MD;
  bf16_t* vT    = v_lin + MD;
  float2* tab   = (float2*)(vT + MD);
  bf16_t* attn_out = x_bf;  // x_bf dead after k_gemm_qkv; rewritten by k_prep
                            // every call -> no cross-call state dependency

  k_prep<<<8448, 256, 0, stream>>>(x, wq, wk, wv, wo, x_bf, wq_bf, wk_bf,
                                   wv_bf, wo_bf, tab);

  k_gemm_qkv<<<768, 256, 0, stream>>>(x_bf, wq_bf, bq, bk, bv, q_lin, k_lin,
                                      v_lin);

  // Q scale folds 1/sqrt(64) AND log2(e) -> QK^T scores land in log2 units.
  k_rope<<<2048, 256, 0, stream>>>(q_lin, tab, 0.125f * 1.4426950408889634f);
  k_rope<<<2048, 256, 0, stream>>>(k_lin, tab, 1.0f);
  k_trans<<<dim3(S / 64, Bn * NH), 256, 0, stream>>>(v_lin, vT);

  k_attn<<<1024, 256, 0, stream>>>(q_lin, k_lin, vT, attn_out);

  k_gemm_out<<<256, 256, 0, stream>>>(attn_out, wo_bf, bo, (float*)d_out);
}

// Round 15
// 124.577 us; speedup vs baseline: 1.0779x; 1.0405x over previous
//
#include <hip/hip_runtime.h>
#include <cstdint>
#include <cstddef>
#include <cmath>

// ---------------------------------------------------------------------------
// MultiHeadAttention (B=2, S=2048, DIM=1024, H=16, HD=64), causal + RoPE.
// R15: occupancy round.
//  - attn: single-buffered K/V (sync stage, R1-proven pattern) -> 24KB LDS,
//    6 blocks/CU (was 4). Mapping/body otherwise = R14 (passing).
//  - gemm_out: 128x64 tiles -> 512 blocks, 2/CU (was 1/CU).
//  - rope Q+K merged into one launch.
// gemm_qkv / prep / trans byte-identical to R14 (passing).
// ---------------------------------------------------------------------------

typedef __bf16 bf16_t;
typedef __bf16 bf16x8 __attribute__((ext_vector_type(8)));
typedef __bf16 bf16x4 __attribute__((ext_vector_type(4)));
typedef float  f32x4  __attribute__((ext_vector_type(4)));

#define DEVFN __device__ __forceinline__

static constexpr int Bn  = 2;
static constexpr int S   = 2048;
static constexpr int DIM = 1024;
static constexpr int NH  = 16;
static constexpr int HD  = 64;
static constexpr int Mrows = Bn * S;        // 4096

DEVFN f32x4 mfma16(bf16x8 a, bf16x8 b, f32x4 c) {
  return __builtin_amdgcn_mfma_f32_16x16x32_bf16(a, b, c, 0, 0, 0);
}

DEVFN void gl_lds16(const bf16_t* g, bf16_t* l) {
  __builtin_amdgcn_global_load_lds(
      (const __attribute__((address_space(1))) unsigned*)g,
      (__attribute__((address_space(3))) unsigned*)l, 16, 0, 0);
}

DEVFN float fast_exp2(float x) { return exp2f(x); }  // -> v_exp_f32

// ---------------------------------------------------------------------------
// One launch: all fp32->bf16 converts + rope table.
__global__ __launch_bounds__(256) void k_prep(
    const float* __restrict__ x, const float* __restrict__ wq,
    const float* __restrict__ wk, const float* __restrict__ wv,
    const float* __restrict__ wo, bf16_t* __restrict__ xb,
    bf16_t* __restrict__ wqb, bf16_t* __restrict__ wkb,
    bf16_t* __restrict__ wvb, bf16_t* __restrict__ wob,
    float2* __restrict__ tab) {
  const int bid = blockIdx.x;
  if (bid < 8192) {
    const float* src;
    bf16_t* dst;
    size_t base;
    if (bid < 4096) {
      src = x; dst = xb; base = (size_t)bid << 10;
    } else {
      int wsel = (bid - 4096) >> 10;
      src = wsel == 0 ? wq : wsel == 1 ? wk : wsel == 2 ? wv : wo;
      dst = wsel == 0 ? wqb : wsel == 1 ? wkb : wsel == 2 ? wvb : wob;
      base = (size_t)((bid - 4096) & 1023) << 10;
    }
    size_t i = base + (size_t)threadIdx.x * 4;
    float4 v = *(const float4*)(src + i);
    bf16x4 o = { (bf16_t)v.x, (bf16_t)v.y, (bf16_t)v.z, (bf16_t)v.w };
    *(bf16x4*)(dst + i) = o;
  } else {
    int i = (bid - 8192) * 256 + threadIdx.x;  // < S*32
    int s = i >> 5, d = i & 31;
    float th = (float)s * expf((float)d * -0.2878231366f);  // ln(10000)/32
    tab[i] = make_float2(cosf(th), sinf(th));
  }
}

// ---------------------------------------------------------------------------
// in-place rope on q (blocks 0-2047, scale sq) and k (2048-4095, scale 1).
__global__ __launch_bounds__(256) void k_rope2(bf16_t* __restrict__ q,
                                               bf16_t* __restrict__ k,
                                               const float2* __restrict__ tab,
                                               float sq) {
  const int bid = blockIdx.x;
  bf16_t* X = bid < 2048 ? q : k;
  const float scale = bid < 2048 ? sq : 1.0f;
  int i = (bid & 2047) * 256 + threadIdx.x;  // chunk of 8 elems
  int row = i >> 7;
  int s = row & (S - 1);
  int p0 = (i & 7) << 2;
  bf16x8 v = *(bf16x8*)(X + (size_t)i * 8);
  bf16x8 o;
#pragma unroll
  for (int j = 0; j < 4; ++j) {
    float x1 = (float)v[2 * j], x2 = (float)v[2 * j + 1];
    float2 cs = tab[s * 32 + p0 + j];
    o[2 * j]     = (bf16_t)((x1 * cs.x - x2 * cs.y) * scale);
    o[2 * j + 1] = (bf16_t)((x1 * cs.y + x2 * cs.x) * scale);
  }
  *(bf16x8*)(X + (size_t)i * 8) = o;
}

// V [b][s][h][d] -> VT [b*h][d][s] (R4-proven body).
__global__ __launch_bounds__(256) void k_trans(const bf16_t* __restrict__ Vin,
                                               bf16_t* __restrict__ VT) {
  __shared__ __align__(16) bf16_t tile[64][72];
  int s0 = blockIdx.x * 64, bh = blockIdx.y;
  int b = bh >> 4, h = bh & 15;
  int t = threadIdx.x;
#pragma unroll
  for (int it = 0; it < 2; ++it) {
    int sl = (t >> 3) + it * 32, d0 = (t & 7) << 3;
    *(bf16x8*)&tile[sl][d0] =
        *(const bf16x8*)(Vin + (size_t)(b * S + s0 + sl) * DIM + h * HD + d0);
  }
  __syncthreads();
  int d = t >> 2, c0 = (t & 3) * 16;
  bf16_t buf[16];
#pragma unroll
  for (int j = 0; j < 16; ++j) buf[j] = tile[c0 + j][d];
  bf16_t* op = VT + ((size_t)bh * HD + d) * S + s0 + c0;
  *(bf16x8*)op = *(bf16x8*)&buf[0];
  *(bf16x8*)(op + 8) = *(bf16x8*)&buf[8];
}

// ---------------------------------------------------------------------------
// GEMM staging, BK=64 tile [128 rows][64 k] per matrix. Source pre-swizzled
// j=((c&7)^(row&7))*8, LDS dest linear; read back with byte-XOR ((row&7)<<4).
DEVFN void stage64(const bf16_t* __restrict__ A, const bf16_t* __restrict__ Bw,
                   bf16_t* Al, bf16_t* Bl, int m0, int n0, int k0, int t,
                   int w) {
#pragma unroll
  for (int ld = 0; ld < 4; ++ld) {
    int c = t + ld * 256;
    int row = c >> 3;
    int j = ((c & 7) ^ (row & 7)) << 3;
    bf16_t* dstA = Al + (size_t)(w * 64 + ld * 256) * 8;
    bf16_t* dstB = Bl + (size_t)(w * 64 + ld * 256) * 8;
    gl_lds16(A + (size_t)(m0 + row) * DIM + k0 + j, dstA);
    gl_lds16(Bw + (size_t)(n0 + row) * DIM + k0 + j, dstB);
  }
}

// ---------------------------------------------------------------------------
// Fused QKV NT GEMM: M=4096, N=3072 (wq|wk|wv contiguous), K=1024. 128x128
// tile, BK=64 (16 iters). 768 blocks, XCD rectangle swizzle. Plain bias
// epilogue -> q_lin/k_lin/v_lin. (Byte-identical to R14.)
__global__ __launch_bounds__(256) void k_gemm_qkv(
    const bf16_t* __restrict__ A, const bf16_t* __restrict__ Wall,
    const float* __restrict__ c0, const float* __restrict__ c1,
    const float* __restrict__ c2, bf16_t* __restrict__ Oq,
    bf16_t* __restrict__ Ok, bf16_t* __restrict__ Ov_) {
  __shared__ __align__(16) bf16_t Al[128 * 64];
  __shared__ __align__(16) bf16_t Bl[128 * 64];
  const int t = threadIdx.x, w = t >> 6, l = t & 63;
  const int lr = l & 15, lc = l >> 4;
  const int lid = blockIdx.x;
  const int xcd = lid & 7, s = lid >> 3;          // s in [0,96)
  const int my = ((xcd >> 1) << 3) + (s & 7);     // [0,32)
  const int nx = (xcd & 1) * 12 + (s >> 3);       // [0,24)
  const int m0 = my * 128, n0g = nx * 128;
  const int z = n0g >> 10, n0l = n0g & 1023;
  const int wr = w >> 1, wc = w & 1;
  f32x4 acc[4][4] = {};

  for (int k0 = 0; k0 < DIM; k0 += 64) {
    __syncthreads();
    stage64(A, Wall, Al, Bl, m0, n0g, k0, t, w);
    asm volatile("s_waitcnt vmcnt(0)" ::: "memory");
    __syncthreads();
    bf16x8 af[2][4], bfr[2][4];
#pragma unroll
    for (int ks = 0; ks < 2; ++ks) {
#pragma unroll
      for (int mi = 0; mi < 4; ++mi) {
        int row = wr * 64 + mi * 16 + lr;
        int off = ((ks * 4 + lc) << 4) ^ ((row & 7) << 4);
        af[ks][mi] = *(const bf16x8*)((const char*)Al + row * 128 + off);
      }
#pragma unroll
      for (int ni = 0; ni < 4; ++ni) {
        int row = wc * 64 + ni * 16 + lr;
        int off = ((ks * 4 + lc) << 4) ^ ((row & 7) << 4);
        bfr[ks][ni] = *(const bf16x8*)((const char*)Bl + row * 128 + off);
      }
    }
    __builtin_amdgcn_s_setprio(1);
#pragma unroll
    for (int ks = 0; ks < 2; ++ks)
#pragma unroll
      for (int mi = 0; mi < 4; ++mi)
#pragma unroll
        for (int ni = 0; ni < 4; ++ni)
          acc[mi][ni] = mfma16(af[ks][mi], bfr[ks][ni], acc[mi][ni]);
    __builtin_amdgcn_s_setprio(0);
  }

  bf16_t* Ov = z == 0 ? Oq : (z == 1 ? Ok : Ov_);
  const float* bias = z == 0 ? c0 : (z == 1 ? c1 : c2);
#pragma unroll
  for (int ni = 0; ni < 4; ++ni) {
    const int col = n0l + wc * 64 + ni * 16 + lr;
    const float bv = bias[col];
#pragma unroll
    for (int mi = 0; mi < 4; ++mi)
#pragma unroll
      for (int r = 0; r < 4; ++r) {
        int row = m0 + wr * 64 + mi * 16 + lc * 4 + r;
        Ov[(size_t)row * DIM + col] = (bf16_t)(acc[mi][ni][r] + bv);
      }
  }
}

// ---------------------------------------------------------------------------
// Out projection: M=4096, N=1024, K=1024. 128x64 tiles -> 512 blocks (2/CU).
// 4 waves x (2x4) MFMA each (per-wave 32x64). Same swizzled BK=64 staging.
__global__ __launch_bounds__(256) void k_gemm_out(
    const bf16_t* __restrict__ A, const bf16_t* __restrict__ Bw,
    const float* __restrict__ bias, float* __restrict__ Ov) {
  __shared__ __align__(16) bf16_t Al[128 * 64];
  __shared__ __align__(16) bf16_t Bl[64 * 64];
  const int t = threadIdx.x, w = t >> 6, l = t & 63;
  const int lr = l & 15, lc = l >> 4;
  const int lid = blockIdx.x;                     // 512 blocks
  const int xcd = lid & 7, s = lid >> 3;          // s in [0,64)
  const int my = ((xcd >> 1) << 3) + (s & 7);     // [0,32)
  const int nx = (xcd & 1) * 8 + (s >> 3);        // [0,16)
  const int m0 = my * 128, n0 = nx * 64;
  f32x4 acc[2][4] = {};

  for (int k0 = 0; k0 < DIM; k0 += 64) {
    __syncthreads();
    // A: 128 rows x 8 chunks = 1024; B: 64 rows x 8 chunks = 512
#pragma unroll
    for (int ld = 0; ld < 4; ++ld) {
      int c = t + ld * 256;
      int row = c >> 3;
      int j = ((c & 7) ^ (row & 7)) << 3;
      gl_lds16(A + (size_t)(m0 + row) * DIM + k0 + j,
               Al + (size_t)(w * 64 + ld * 256) * 8);
    }
#pragma unroll
    for (int ld = 0; ld < 2; ++ld) {
      int c = t + ld * 256;
      int row = c >> 3;
      int j = ((c & 7) ^ (row & 7)) << 3;
      gl_lds16(Bw + (size_t)(n0 + row) * DIM + k0 + j,
               Bl + (size_t)(w * 64 + ld * 256) * 8);
    }
    asm volatile("s_waitcnt vmcnt(0)" ::: "memory");
    __syncthreads();
    bf16x8 af[2][2], bfr[2][4];
#pragma unroll
    for (int ks = 0; ks < 2; ++ks) {
#pragma unroll
      for (int mi = 0; mi < 2; ++mi) {
        int row = w * 32 + mi * 16 + lr;
        int off = ((ks * 4 + lc) << 4) ^ ((row & 7) << 4);
        af[ks][mi] = *(const bf16x8*)((const char*)Al + row * 128 + off);
      }
#pragma unroll
      for (int ni = 0; ni < 4; ++ni) {
        int row = ni * 16 + lr;
        int off = ((ks * 4 + lc) << 4) ^ ((row & 7) << 4);
        bfr[ks][ni] = *(const bf16x8*)((const char*)Bl + row * 128 + off);
      }
    }
    __builtin_amdgcn_s_setprio(1);
#pragma unroll
    for (int ks = 0; ks < 2; ++ks)
#pragma unroll
      for (int mi = 0; mi < 2; ++mi)
#pragma unroll
        for (int ni = 0; ni < 4; ++ni)
          acc[mi][ni] = mfma16(af[ks][mi], bfr[ks][ni], acc[mi][ni]);
    __builtin_amdgcn_s_setprio(0);
  }

#pragma unroll
  for (int ni = 0; ni < 4; ++ni) {
    int col = n0 + ni * 16 + lr;
    float bv = bias[col];
#pragma unroll
    for (int mi = 0; mi < 2; ++mi)
#pragma unroll
      for (int r = 0; r < 4; ++r) {
        int row = m0 + w * 32 + mi * 16 + lc * 4 + r;
        Ov[(size_t)row * DIM + col] = acc[mi][ni][r] + bv;
      }
  }
}

// ---------------------------------------------------------------------------
// Causal flash attention, R15: KVBLK=64, one q-tile per block, grid 1024,
// descending-workload dispatch, SINGLE-buffered K/V (sync stage — R1-proven
// pattern) -> 24KB LDS -> 6 blocks/CU. Body otherwise = R14 (passing).
DEVFN void stage_kv(const bf16_t* __restrict__ Kc,
                    const bf16_t* __restrict__ VT, bf16_t* Kb, bf16_t* Vb,
                    int b, int bh, int h, int k0, int tid, int w) {
#pragma unroll
  for (int ld = 0; ld < 2; ++ld) {
    int c = tid + ld * 256;
    int row = c >> 3;
    int j = ((c & 7) ^ (row & 7)) << 3;  // pre-swizzled source chunk
    bf16_t* dstK = Kb + (size_t)(w * 64 + ld * 256) * 8;
    bf16_t* dstV = Vb + (size_t)(w * 64 + ld * 256) * 8;
    gl_lds16(Kc + (size_t)(b * S + k0 + row) * DIM + h * HD + j, dstK);
    gl_lds16(VT + ((size_t)bh * HD + row) * S + k0 + j, dstV);
  }
}

__global__ __launch_bounds__(256) void k_attn(const bf16_t* __restrict__ Q,
                                              const bf16_t* __restrict__ Kc,
                                              const bf16_t* __restrict__ VT,
                                              bf16_t* __restrict__ O) {
  __shared__ __align__(16) bf16_t Kl[64 * 64];
  __shared__ __align__(16) bf16_t Vl[64 * 64];
  __shared__ __align__(16) bf16_t Pl[4][16 * 64];
  const int tid = threadIdx.x, w = tid >> 6, l = tid & 63;
  const int lr = l & 15, lc = l >> 4;
  const int lid = blockIdx.x;
  const int xcd = lid & 7;
  const int rest = lid >> 3;          // 0..127
  const int t_ord = rest >> 2;        // 0..31
  const int hh = rest & 3;
  const int tile = 31 - t_ord;        // big tiles dispatch first
  const int bh = xcd * 4 + hh;
  const int b = bh >> 4, h = bh & 15;
  char* Pw = (char*)&Pl[w][0];

  const int q0 = tile * 64;
  const int nt = tile + 1;

  bf16x8 qf[2];
  {
    const bf16_t* qp =
        Q + (size_t)(b * S + q0 + w * 16 + lr) * DIM + h * HD + lc * 8;
    qf[0] = *(const bf16x8*)qp;
    qf[1] = *(const bf16x8*)(qp + 32);
  }
  f32x4 o[4] = {};
  float m_run = -INFINITY;
  float rowsum = 0.f;

#pragma unroll 1
  for (int it = 0; it < nt; ++it) {
    stage_kv(Kc, VT, &Kl[0], &Vl[0], b, bh, h, it * 64, tid, w);
    asm volatile("s_waitcnt vmcnt(0)" ::: "memory");
    __builtin_amdgcn_s_barrier();
    __builtin_amdgcn_sched_barrier(0);

    // swapped QK^T: lane (lr,lc) holds S'[q=w*16+lr][k=ni*16+lc*4+r]
    f32x4 s[4] = {};
    __builtin_amdgcn_s_setprio(1);
#pragma unroll
    for (int ks = 0; ks < 2; ++ks) {
#pragma unroll
      for (int ni = 0; ni < 4; ++ni) {
        int row = ni * 16 + lr;
        int off = (ks * 64 + lc * 16) ^ ((row & 7) << 4);
        bf16x8 kf = *(const bf16x8*)((const char*)Kl + row * 128 + off);
        s[ni] = mfma16(kf, qf[ks], s[ni]);
      }
    }
    __builtin_amdgcn_s_setprio(0);

    if (it == tile) {  // diagonal tile: mask k_local > q_local
      const int qloc = w * 16 + lr;
#pragma unroll
      for (int ni = 0; ni < 4; ++ni)
#pragma unroll
        for (int r = 0; r < 4; ++r)
          if (ni * 16 + lc * 4 + r > qloc) s[ni][r] = -INFINITY;
    }

    // row max: paired tree, then 2 cross-lane reduces
    float m01 = fmaxf(fmaxf(s[0][0], s[0][1]), fmaxf(s[0][2], s[0][3]));
    float m23 = fmaxf(fmaxf(s[1][0], s[1][1]), fmaxf(s[1][2], s[1][3]));
    float m45 = fmaxf(fmaxf(s[2][0], s[2][1]), fmaxf(s[2][2], s[2][3]));
    float m67 = fmaxf(fmaxf(s[3][0], s[3][1]), fmaxf(s[3][2], s[3][3]));
    float pm = fmaxf(fmaxf(m01, m23), fmaxf(m45, m67));
    pm = fmaxf(pm, __shfl_xor(pm, 16));
    pm = fmaxf(pm, __shfl_xor(pm, 32));

    // defer-max (log2 units): rescale only if max grew past 8 (P <= 2^8)
    if (__ballot(pm > m_run + 8.f)) {
      float mn = fmaxf(m_run, pm);
      float alpha = fast_exp2(m_run - mn);
      m_run = mn;
      rowsum *= alpha;
#pragma unroll
      for (int r = 0; r < 4; ++r) {
        float aq = __shfl(alpha, lc * 4 + r);
#pragma unroll
        for (int ni = 0; ni < 4; ++ni) o[ni][r] *= aq;
      }
    }

    // P = exp2(s - m_run); in-lane partial sum; pack to LDS as b64
    float rs = 0.f;
#pragma unroll
    for (int ni = 0; ni < 4; ++ni) {
      float p0 = fast_exp2(s[ni][0] - m_run);
      float p1 = fast_exp2(s[ni][1] - m_run);
      float p2 = fast_exp2(s[ni][2] - m_run);
      float p3 = fast_exp2(s[ni][3] - m_run);
      rs += (p0 + p1) + (p2 + p3);
      bf16x4 pb = { (bf16_t)p0, (bf16_t)p1, (bf16_t)p2, (bf16_t)p3 };
      *(bf16x4*)(Pw + (lr * 128 + ((ni * 32 + lc * 8) ^ ((lr & 7) << 4)))) =
          pb;
    }
    rs += __shfl_xor(rs, 16);
    rs += __shfl_xor(rs, 32);
    rowsum += rs;

    // PV: o[ni] += P(16x64) * V(64x64)
    __builtin_amdgcn_s_setprio(1);
#pragma unroll
    for (int ks = 0; ks < 2; ++ks) {
      int off = ks * 64 + lc * 16;
      bf16x8 pa = *(const bf16x8*)(Pw + lr * 128 + (off ^ ((lr & 7) << 4)));
#pragma unroll
      for (int ni = 0; ni < 4; ++ni) {
        int vrow = ni * 16 + lr;
        bf16x8 vb = *(const bf16x8*)((const char*)Vl + vrow * 128 +
                                     (off ^ ((vrow & 7) << 4)));
        o[ni] = mfma16(pa, vb, o[ni]);
      }
    }
    __builtin_amdgcn_s_setprio(0);

    __builtin_amdgcn_s_barrier();  // all reads done before next stage
  }

  // normalize + store. o[ni]: q = q0 + w*16 + lc*4 + r, d = ni*16 + lr
  float inv[4];
#pragma unroll
  for (int r = 0; r < 4; ++r) inv[r] = 1.0f / __shfl(rowsum, lc * 4 + r);
#pragma unroll
  for (int ni = 0; ni < 4; ++ni)
#pragma unroll
    for (int r = 0; r < 4; ++r) {
      int qr = q0 + w * 16 + lc * 4 + r;
      float v = o[ni][r] * inv[r];
      O[(size_t)(b * S + qr) * DIM + h * HD + ni * 16 + lr] = (bf16_t)v;
    }
}

// ---------------------------------------------------------------------------
extern "C" void kernel_launch(void* const* d_in, const int* in_sizes, int n_in,
                              void* d_out, int out_size, void* d_ws,
                              size_t ws_size, hipStream_t stream) {
  const float* x  = (const float*)d_in[0];
  const float* wq = (const float*)d_in[1];
  const float* bq = (const float*)d_in[2];
  const float* wk = (const float*)d_in[3];
  const float* bk = (const float*)d_in[4];
  const float* wv = (const float*)d_in[5];
  const float* bv = (const float*)d_in[6];
  const float* wo = (const float*)d_in[7];
  const float* bo = (const float*)d_in[8];

  const size_t MD = (size_t)Mrows * DIM;   // 4194304
  const size_t WD = (size_t)DIM * DIM;     // 1048576
  bf16_t* W = (bf16_t*)d_ws;
  bf16_t* x_bf  = W;
  bf16_t* wq_bf = x_bf + MD;               // wq|wk|wv contiguous = [3072][1024]
  bf16_t* wk_bf = wq_bf + WD;
  bf16_t* wv_bf = wk_bf + WD;
  bf16_t* wo_bf = wv_bf + WD;
  bf16_t* q_lin = wo_bf + WD;
  bf16_t* k_lin = q_lin + MD;
  bf16_t* v_lin = k_lin + MD;
  bf16_t* vT    = v_lin + MD;
  float2* tab   = (float2*)(vT + MD);
  bf16_t* attn_out = x_bf;  // x_bf dead after k_gemm_qkv; rewritten by k_prep
                            // every call -> no cross-call state dependency

  k_prep<<<8448, 256, 0, stream>>>(x, wq, wk, wv, wo, x_bf, wq_bf, wk_bf,
                                   wv_bf, wo_bf, tab);

  k_gemm_qkv<<<768, 256, 0, stream>>>(x_bf, wq_bf, bq, bk, bv, q_lin, k_lin,
                                      v_lin);

  // Q scale folds 1/sqrt(64) AND log2(e) -> QK^T scores land in log2 units.
  k_rope2<<<4096, 256, 0, stream>>>(q_lin, k_lin, tab,
                                    0.125f * 1.4426950408889634f);
  k_trans<<<dim3(S / 64, Bn * NH), 256, 0, stream>>>(v_lin, vT);

  k_attn<<<1024, 256, 0, stream>>>(q_lin, k_lin, vT, attn_out);

  k_gemm_out<<<512, 256, 0, stream>>>(attn_out, wo_bf, bo, (float*)d_out);
}